// Round 1
// baseline (213036.670 us; speedup 1.0000x reference)
//
#include <hip/hip_runtime.h>
#include <math.h>

#define BATCH 128
#define TDEC  550
#define TENC  500
#define EDIM  512
#define VOC   31

// ---------------- workspace layout (float offsets) ----------------
#define SZ65536  65536u
#define OFF_WA   0u                          // [2048][1024]  cols 0..511 = M (s-part), 512..1023 = w_hh0
#define OFF_WB   (OFF_WA + 2048u*1024u)      // [2048][1024]  cols 0..511 = w_ih1,      512..1023 = w_hh1
#define OFF_GM   (OFF_WB + 2048u*1024u)      // [512][1024]   cols 0..511 = w_o2c[:, :512], 512.. = M2 (s-part)
#define OFF_E2G  (OFF_GM + 512u*1024u)       // [31][2048]    E2G[v][g] = sum_e emb[v,e]*w_ih0[g,e]
#define OFF_BA   (OFF_E2G + 31u*2048u)       // [2048] b_ih0+b_hh0
#define OFF_BB   (OFF_BA + 2048u)            // [2048] b_ih1+b_hh1
#define OFF_BG   (OFF_BB + 2048u)            // [512]  b_o2c
#define OFF_ST   (OFF_BG + 512u)             // sT   [512][128]
#define OFF_H0T0 (OFF_ST   + SZ65536)        // h0T parity 0
#define OFF_H0T1 (OFF_H0T0 + SZ65536)        // h0T parity 1
#define OFF_H1T0 (OFF_H0T1 + SZ65536)
#define OFF_H1T1 (OFF_H1T0 + SZ65536)
#define OFF_C0T  (OFF_H1T1 + SZ65536)
#define OFF_C1T  (OFF_C0T  + SZ65536)
#define OFF_Q    (OFF_C1T  + SZ65536)        // q [128][512]
#define OFF_P    (OFF_Q    + SZ65536)        // p (unnormalized softmax) [128][512] (500 used)
#define OFF_PM   (OFF_P    + SZ65536)        // partial max [128][2]
#define OFF_PL   (OFF_PM + 256u)             // partial sum [128][2]
#define OFF_PS   (OFF_PL + 256u)             // partial s   [128][2][512]
#define OFF_LB   (OFF_PS + 131072u)          // logits dbl-buf [2][128][32]
#define OFF_BAR  (OFF_LB + 8192u)            // barrier counters (2 x u32) + pad

// ---------------- init kernel 1: copies / biases / zeros ----------------
__global__ void initCopy(const float* __restrict__ w_hh0, const float* __restrict__ w_ih1,
                         const float* __restrict__ w_hh1, const float* __restrict__ w_o2c,
                         const float* __restrict__ b_ih0, const float* __restrict__ b_hh0,
                         const float* __restrict__ b_ih1, const float* __restrict__ b_hh1,
                         const float* __restrict__ b_o2c, float* __restrict__ ws)
{
  const unsigned n0 = 2048u*512u;      // WA right
  const unsigned n1 = 2048u*512u;      // WB left
  const unsigned n2 = 2048u*512u;      // WB right
  const unsigned n3 = 512u*512u;       // GM left
  const unsigned nz = 7u*SZ65536;      // state zeros (sT,h0T0,h0T1,h1T0,h1T1,c0T,c1T contiguous)
  const unsigned NT = n0+n1+n2+n3 + 2048u+2048u+512u + nz + 8192u + 16u;
  for (unsigned i = blockIdx.x*blockDim.x + threadIdx.x; i < NT; i += gridDim.x*blockDim.x) {
    unsigned j = i;
    if (j < n0) { unsigned r = j>>9, k = j&511u;
      ws[OFF_WA + r*1024u + 512u + k] = w_hh0[j]; continue; }
    j -= n0;
    if (j < n1) { unsigned r = j>>9, k = j&511u;
      ws[OFF_WB + r*1024u + k] = w_ih1[j]; continue; }
    j -= n1;
    if (j < n2) { unsigned r = j>>9, k = j&511u;
      ws[OFF_WB + r*1024u + 512u + k] = w_hh1[j]; continue; }
    j -= n2;
    if (j < n3) { unsigned r = j>>9, k = j&511u;
      ws[OFF_GM + r*1024u + k] = w_o2c[r*1024u + k]; continue; }
    j -= n3;
    if (j < 2048u) { ws[OFF_BA + j] = b_ih0[j] + b_hh0[j]; continue; }
    j -= 2048u;
    if (j < 2048u) { ws[OFF_BB + j] = b_ih1[j] + b_hh1[j]; continue; }
    j -= 2048u;
    if (j < 512u)  { ws[OFF_BG + j] = b_o2c[j]; continue; }
    j -= 512u;
    if (j < nz)    { ws[OFF_ST + j] = 0.f; continue; }
    j -= nz;
    if (j < 8192u) {
      unsigned buf = j>>12, v = j & 31u;
      ws[OFF_LB + j] = (buf==1u && v==0u) ? 1e9f : 0.f;   // force argmax -> SOS(=0) at t=0
      continue; }
    j -= 8192u;
    ((unsigned*)(ws + OFF_BAR))[j] = 0u;
  }
}

// ---------------- init kernel 2: folded weight GEMMs ----------------
__global__ void initGemm(const float* __restrict__ w_ih0, const float* __restrict__ w_o2c,
                         const float* __restrict__ wvm, const float* __restrict__ emb,
                         float* __restrict__ ws)
{
  const unsigned n0 = 2048u*512u;   // M     -> WA left
  const unsigned n1 = 512u*512u;    // M2    -> GM right
  const unsigned n2 = 31u*2048u;    // E2G
  const unsigned NT = n0+n1+n2;
  for (unsigned i = blockIdx.x*blockDim.x + threadIdx.x; i < NT; i += gridDim.x*blockDim.x) {
    if (i < n0) {
      unsigned r = i>>9, d = i&511u;
      const float* a = w_ih0 + (size_t)r*1024u + 512u;
      const float* b = wvm + (size_t)d*512u;
      float s = 0.f;
      for (int k = 0; k < 512; ++k) s = fmaf(a[k], b[k], s);
      ws[OFF_WA + r*1024u + d] = s;
    } else if (i < n0+n1) {
      unsigned j = i - n0; unsigned r = j>>9, d = j&511u;
      const float* a = w_o2c + (size_t)r*1024u + 512u;
      const float* b = wvm + (size_t)d*512u;
      float s = 0.f;
      for (int k = 0; k < 512; ++k) s = fmaf(a[k], b[k], s);
      ws[OFF_GM + r*1024u + 512u + d] = s;
    } else {
      unsigned j = i - n0 - n1; unsigned v = j>>11, g = j&2047u;
      const float* a = emb + (size_t)v*512u;
      const float* b = w_ih0 + (size_t)g*1024u;
      float s = 0.f;
      for (int k = 0; k < 512; ++k) s = fmaf(a[k], b[k], s);
      ws[OFF_E2G + v*2048u + g] = s;
    }
  }
}

// ---------------- grid barrier (monotonic generation) ----------------
__device__ __forceinline__ void gridbar(unsigned* cnt, unsigned* gen, unsigned& tgt)
{
  __syncthreads();
  if (threadIdx.x == 0) {
    tgt += 1u;
    unsigned old = __hip_atomic_fetch_add(cnt, 1u, __ATOMIC_ACQ_REL, __HIP_MEMORY_SCOPE_AGENT);
    if (old == tgt*256u - 1u) {
      __hip_atomic_fetch_add(gen, 1u, __ATOMIC_ACQ_REL, __HIP_MEMORY_SCOPE_AGENT);
    } else {
      while (__hip_atomic_load(gen, __ATOMIC_ACQUIRE, __HIP_MEMORY_SCOPE_AGENT) < tgt)
        __builtin_amdgcn_s_sleep(2);
    }
  }
  __syncthreads();
}

__device__ __forceinline__ float sigm(float x) { return 1.f/(1.f + expf(-x)); }

// ---------------- main persistent kernel ----------------
__launch_bounds__(256)
__global__ void speller_main(const float* __restrict__ enc, const float* __restrict__ emb,
                             const float* __restrict__ wk,  const float* __restrict__ bcp,
                             float* __restrict__ ws, float* __restrict__ out)
{
  __shared__ __align__(16) float smem[8704];
  const int tid  = threadIdx.x;
  const int blk  = blockIdx.x;
  const int lane = tid & 63;
  const int wv   = tid >> 6;
  unsigned* bar_cnt = (unsigned*)(ws + OFF_BAR);
  unsigned* bar_gen = bar_cnt + 1;
  unsigned tgt = 0;

  float* rawout  = out;                                   // [128][550][31]
  float* attnout = out + (size_t)BATCH*TDEC*VOC;          // [128][550][500]

  for (int t = 0; t < TDEC; ++t) {
    const int p = t & 1;
    float*       h0_cur  = ws + (p ? OFF_H0T1 : OFF_H0T0);
    const float* h0_prev = ws + (p ? OFF_H0T0 : OFF_H0T1);
    float*       h1_cur  = ws + (p ? OFF_H1T1 : OFF_H1T0);
    const float* h1_prev = ws + (p ? OFF_H1T0 : OFF_H1T1);

    // ================= Phase A : argmax(prev logits) + LSTM0 =================
    {
      const int bh = blk >> 7, jg = blk & 127;
      const int b  = bh*64 + lane;
      const int j0 = jg*4;
      const float* Lb = ws + OFF_LB + (unsigned)(p ^ 1)*4096u;
      float best = -3.4e38f; int sym = 0;
      for (int v = 0; v < VOC; ++v) {
        float f = Lb[b*32 + v] + bcp[v];
        if (f > best) { best = f; sym = v; }
      }
      if (jg == 0) {
        if (t > 0) {
          for (int i2 = tid; i2 < 64*VOC; i2 += 256) {
            int bl = i2 / VOC, v = i2 % VOC;
            int bb = bh*64 + bl;
            rawout[((size_t)bb*TDEC + (t-1))*VOC + v] = Lb[bb*32 + v] + bcp[v];
          }
        }
        float* Lz = ws + OFF_LB + (unsigned)p*4096u;
        for (int i2 = tid; i2 < 2048; i2 += 256) {
          int bl = i2 >> 5, v = i2 & 31;
          Lz[(bh*64+bl)*32 + v] = 0.f;
        }
      }
      float acc[16];
      #pragma unroll
      for (int u = 0; u < 16; ++u) acc[u] = 0.f;
      const int khalf = wv >> 1;               // 0: s-part (via M), 1: h0-part (w_hh0)
      const int k0 = (wv & 1)*256;
      const float* xsrc = (khalf ? h0_prev : (ws + OFF_ST)) + (size_t)k0*128 + b;
      const float* wsrc = (ws + OFF_WA) + khalf*512 + k0;
      for (int k = 0; k < 256; ++k) {
        float xv = xsrc[(size_t)k*128];
        #pragma unroll
        for (int u = 0; u < 16; ++u) {
          int gi = u & 3, jj = u >> 2;
          acc[u] = fmaf(xv, wsrc[(size_t)(gi*512 + j0 + jj)*1024 + k], acc[u]);
        }
      }
      float* lacc = smem;
      #pragma unroll
      for (int u = 0; u < 16; ++u) lacc[wv*1024 + lane*16 + u] = acc[u];
      __syncthreads();
      {
        const int bl = tid & 63, jj = tid >> 6;
        const int bb = bh*64 + bl;
        const int j  = j0 + jj;
        float gv[4];
        #pragma unroll
        for (int gi = 0; gi < 4; ++gi) {
          float s = 0.f;
          #pragma unroll
          for (int w = 0; w < 4; ++w) s += lacc[w*1024 + bl*16 + jj*4 + gi];
          s += (ws + OFF_E2G)[(size_t)sym*2048 + gi*512 + j];
          s += (ws + OFF_BA)[gi*512 + j];
          gv[gi] = s;
        }
        float ig = sigm(gv[0]), fg = sigm(gv[1]);
        float gg = tanhf(gv[2]), og = sigm(gv[3]);
        float cold = (ws + OFF_C0T)[(size_t)j*128 + bb];
        float cnew = fg*cold + ig*gg;
        (ws + OFF_C0T)[(size_t)j*128 + bb] = cnew;
        h0_cur[(size_t)j*128 + bb] = og*tanhf(cnew);
      }
    }
    gridbar(bar_cnt, bar_gen, tgt);

    // ================= Phase B : LSTM1 =================
    {
      const int bh = blk >> 7, jg = blk & 127;
      const int b  = bh*64 + lane;
      const int j0 = jg*4;
      float acc[16];
      #pragma unroll
      for (int u = 0; u < 16; ++u) acc[u] = 0.f;
      const int khalf = wv >> 1;               // 0: h0(t) via w_ih1, 1: h1(t-1) via w_hh1
      const int k0 = (wv & 1)*256;
      const float* xsrc = (khalf ? h1_prev : (const float*)h0_cur) + (size_t)k0*128 + b;
      const float* wsrc = (ws + OFF_WB) + khalf*512 + k0;
      for (int k = 0; k < 256; ++k) {
        float xv = xsrc[(size_t)k*128];
        #pragma unroll
        for (int u = 0; u < 16; ++u) {
          int gi = u & 3, jj = u >> 2;
          acc[u] = fmaf(xv, wsrc[(size_t)(gi*512 + j0 + jj)*1024 + k], acc[u]);
        }
      }
      float* lacc = smem;
      #pragma unroll
      for (int u = 0; u < 16; ++u) lacc[wv*1024 + lane*16 + u] = acc[u];
      __syncthreads();
      {
        const int bl = tid & 63, jj = tid >> 6;
        const int bb = bh*64 + bl;
        const int j  = j0 + jj;
        float gv[4];
        #pragma unroll
        for (int gi = 0; gi < 4; ++gi) {
          float s = 0.f;
          #pragma unroll
          for (int w = 0; w < 4; ++w) s += lacc[w*1024 + bl*16 + jj*4 + gi];
          s += (ws + OFF_BB)[gi*512 + j];
          gv[gi] = s;
        }
        float ig = sigm(gv[0]), fg = sigm(gv[1]);
        float gg = tanhf(gv[2]), og = sigm(gv[3]);
        float cold = (ws + OFF_C1T)[(size_t)j*128 + bb];
        float cnew = fg*cold + ig*gg;
        (ws + OFF_C1T)[(size_t)j*128 + bb] = cnew;
        h1_cur[(size_t)j*128 + bb] = og*tanhf(cnew);
      }
    }
    gridbar(bar_cnt, bar_gen, tgt);

    // ================= Phase Q : q = h1 @ wk^T =================
    {
      const int bh = blk >> 7, eg = blk & 127;
      const int b  = bh*64 + lane;
      const int e0 = eg*4;
      float qa[4] = {0.f,0.f,0.f,0.f};
      const int k0 = wv*128;
      const float* xsrc = h1_cur + (size_t)k0*128 + b;
      const float* wsrc = wk + k0;
      for (int k = 0; k < 128; ++k) {
        float xv = xsrc[(size_t)k*128];
        #pragma unroll
        for (int u = 0; u < 4; ++u)
          qa[u] = fmaf(xv, wsrc[(size_t)(e0+u)*512 + k], qa[u]);
      }
      float* lacc = smem;
      #pragma unroll
      for (int u = 0; u < 4; ++u) lacc[wv*256 + lane*4 + u] = qa[u];
      __syncthreads();
      {
        const int bl = tid & 63, ee = tid >> 6;
        float s = 0.f;
        #pragma unroll
        for (int w = 0; w < 4; ++w) s += lacc[w*256 + bl*4 + ee];
        (ws + OFF_Q)[(size_t)(bh*64+bl)*512 + e0 + ee] = s;
      }
    }
    gridbar(bar_cnt, bar_gen, tgt);

    // ================= Phase C : energy + softmax partials + s partials =================
    {
      const int b = blk >> 1, tau = blk & 1;
      const int tbase = tau*250;
      float* q_lds = smem;        // 512
      float* red   = smem + 512;  // 256
      float* p_l   = smem + 768;  // 256
      q_lds[tid]       = (ws + OFF_Q)[(size_t)b*512 + tid];
      q_lds[tid + 256] = (ws + OFF_Q)[(size_t)b*512 + 256 + tid];
      __syncthreads();
      float e = -3.4e38f;
      if (tid < 250) {
        const float4* erow = (const float4*)(enc + ((size_t)b*TENC + tbase + tid)*EDIM);
        const float4* q4 = (const float4*)q_lds;
        float a = 0.f;
        for (int k = 0; k < 128; ++k) {
          float4 ev = erow[k]; float4 qv = q4[k];
          a = fmaf(ev.x, qv.x, a); a = fmaf(ev.y, qv.y, a);
          a = fmaf(ev.z, qv.z, a); a = fmaf(ev.w, qv.w, a);
        }
        e = a;
      }
      red[tid] = e;
      __syncthreads();
      for (int sft = 128; sft > 0; sft >>= 1) {
        if (tid < sft) red[tid] = fmaxf(red[tid], red[tid + sft]);
        __syncthreads();
      }
      float m = red[0];
      __syncthreads();
      float pv = (tid < 250) ? expf(e - m) : 0.f;
      p_l[tid] = pv;
      red[tid] = pv;
      __syncthreads();
      for (int sft = 128; sft > 0; sft >>= 1) {
        if (tid < sft) red[tid] += red[tid + sft];
        __syncthreads();
      }
      float l = red[0];
      if (tid < 250) (ws + OFF_P)[(size_t)b*512 + tbase + tid] = pv;
      if (tid == 0) { (ws+OFF_PM)[b*2+tau] = m; (ws+OFF_PL)[b*2+tau] = l; }
      __syncthreads();
      {
        const int d0 = tid*2;
        float s0 = 0.f, s1 = 0.f;
        const float* ebase = enc + ((size_t)b*TENC + tbase)*EDIM + d0;
        for (int tt = 0; tt < 250; ++tt) {
          float w = p_l[tt];
          float2 ev = *(const float2*)(ebase + (size_t)tt*EDIM);
          s0 = fmaf(w, ev.x, s0); s1 = fmaf(w, ev.y, s1);
        }
        float* psd = ws + OFF_PS + (size_t)(b*2+tau)*512;
        psd[d0] = s0; psd[d0+1] = s1;
      }
    }
    gridbar(bar_cnt, bar_gen, tgt);

    // ================= Phase D : combine + attn out + o2c + logits partials =================
    {
      const int bt = blk >> 4, it = blk & 15;      // 16 b-tiles x 16 i-tiles
      const int b0 = bt*8, i0 = it*32;
      float* xo  = smem;            // [8][1032]  ([h1(512) ; s(512)] per b, padded)
      float* scs = smem + 8256;     // [8][2]
      float* hid = smem + 8272;     // [8][33]
      if (tid < 8) {
        const int bb = b0 + tid;
        float m0 = (ws+OFF_PM)[bb*2], m1 = (ws+OFF_PM)[bb*2+1];
        float l0 = (ws+OFF_PL)[bb*2], l1 = (ws+OFF_PL)[bb*2+1];
        float m = fmaxf(m0, m1);
        float a0 = expf(m0 - m), a1 = expf(m1 - m);
        float li = 1.f/(a0*l0 + a1*l1);
        scs[tid*2] = a0*li; scs[tid*2+1] = a1*li;
      }
      __syncthreads();
      for (int i2 = tid; i2 < 8*512; i2 += 256) {
        int bl = i2 & 7, k = i2 >> 3;
        xo[bl*1032 + k] = h1_cur[(size_t)k*128 + b0 + bl];
      }
      for (int i2 = tid; i2 < 8*512; i2 += 256) {
        int bl = i2 & 7, d = i2 >> 3;
        const float* ps = ws + OFF_PS + (size_t)((b0+bl)*2)*512;
        xo[bl*1032 + 512 + d] = scs[bl*2]*ps[d] + scs[bl*2+1]*ps[512 + d];
      }
      __syncthreads();
      {
        const int bl = tid & 7, il = tid >> 3;
        const int row = i0 + il;
        float acc = 0.f;
        const float4* Gr = (const float4*)(ws + OFF_GM + (size_t)row*1024);
        const float4* xr = (const float4*)(xo + bl*1032);
        for (int k = 0; k < 256; ++k) {
          float4 g = Gr[k], x = xr[k];
          acc = fmaf(g.x, x.x, acc); acc = fmaf(g.y, x.y, acc);
          acc = fmaf(g.z, x.z, acc); acc = fmaf(g.w, x.w, acc);
        }
        hid[bl*33 + il] = fmaxf(acc + (ws+OFF_BG)[row], 0.f);
      }
      if (it == 0) {
        for (int i2 = tid; i2 < 8*TENC; i2 += 256) {
          int bl2 = i2 / TENC, tt = i2 % TENC;
          float sc = (tt < 250) ? scs[bl2*2] : scs[bl2*2+1];
          attnout[((size_t)(b0+bl2)*TDEC + t)*TENC + tt] =
              (ws+OFF_P)[(size_t)(b0+bl2)*512 + tt] * sc;
        }
        for (int i2 = tid; i2 < 8*512; i2 += 256) {
          int bl2 = i2 & 7, d = i2 >> 3;
          (ws+OFF_ST)[(size_t)d*128 + b0 + bl2] = xo[bl2*1032 + 512 + d];
        }
      }
      __syncthreads();
      {
        float* Lw = ws + OFF_LB + (unsigned)p*4096u;
        for (int i2 = tid; i2 < 8*VOC; i2 += 256) {
          int bl2 = i2 & 7, v = i2 >> 3;
          float s = 0.f;
          const float* er = emb + (size_t)v*512 + i0;
          #pragma unroll
          for (int ii = 0; ii < 32; ++ii) s += hid[bl2*33 + ii]*er[ii];
          atomicAdd(&Lw[(b0+bl2)*32 + v], s);
        }
      }
    }
    gridbar(bar_cnt, bar_gen, tgt);
  } // t loop

  // final logits row (t = 549)
  if (blk < 2) {
    const float* Lb = ws + OFF_LB + (unsigned)((TDEC-1)&1)*4096u;
    for (int i2 = tid; i2 < 64*VOC; i2 += 256) {
      int bl = i2 / VOC, v = i2 % VOC;
      int bb = blk*64 + bl;
      rawout[((size_t)bb*TDEC + (TDEC-1))*VOC + v] = Lb[bb*32 + v] + bcp[v];
    }
  }
}

// ---------------- launch ----------------
extern "C" void kernel_launch(void* const* d_in, const int* in_sizes, int n_in,
                              void* d_out, int out_size, void* d_ws, size_t ws_size,
                              hipStream_t stream)
{
  (void)in_sizes; (void)n_in; (void)out_size; (void)ws_size;
  const float* enc   = (const float*)d_in[0];
  const float* emb   = (const float*)d_in[1];
  const float* w_ih0 = (const float*)d_in[2];
  const float* w_hh0 = (const float*)d_in[3];
  const float* b_ih0 = (const float*)d_in[4];
  const float* b_hh0 = (const float*)d_in[5];
  const float* w_ih1 = (const float*)d_in[6];
  const float* w_hh1 = (const float*)d_in[7];
  const float* b_ih1 = (const float*)d_in[8];
  const float* b_hh1 = (const float*)d_in[9];
  const float* wk    = (const float*)d_in[10];
  const float* wvm   = (const float*)d_in[11];
  const float* w_o2c = (const float*)d_in[12];
  const float* b_o2c = (const float*)d_in[13];
  const float* bcp   = (const float*)d_in[14];
  float* ws   = (float*)d_ws;
  float* outp = (float*)d_out;

  initCopy<<<2048, 256, 0, stream>>>(w_hh0, w_ih1, w_hh1, w_o2c,
                                     b_ih0, b_hh0, b_ih1, b_hh1, b_o2c, ws);
  initGemm<<<2048, 256, 0, stream>>>(w_ih0, w_o2c, wvm, emb, ws);
  speller_main<<<256, 256, 0, stream>>>(enc, emb, wk, bcp, ws, outp);
}

// Round 2
// 174714.685 us; speedup vs baseline: 1.2193x; 1.2193x over previous
//
#include <hip/hip_runtime.h>
#include <math.h>

#define BATCH 128
#define TDEC  550
#define TENC  500
#define EDIM  512
#define VOC   31
#define NBLK  256
#define NTHR  512

// ---------------- workspace layout (float offsets) ----------------
#define OFF_WA   0u                          // [2048][1024] cols 0..511 = M (s-part), 512..1023 = w_hh0
#define OFF_WB   (OFF_WA + 2097152u)         // [2048][1024] cols 0..511 = w_ih1, 512..1023 = w_hh1
#define OFF_GM   (OFF_WB + 2097152u)         // [512][1024]  cols 0..511 = w_o2c[:, :512], 512.. = M2
#define OFF_E2G  (OFF_GM + 524288u)          // [31][2048]
#define OFF_BA   (OFF_E2G + 63488u)          // [2048]
#define OFF_BB   (OFF_BA + 2048u)            // [2048]
#define OFF_BG   (OFF_BB + 2048u)            // [512]
#define OFF_ST   (OFF_BG + 512u)             // s~ [512][128]
#define OFF_H0T0 (OFF_ST   + 65536u)
#define OFF_H0T1 (OFF_H0T0 + 65536u)
#define OFF_H1T0 (OFF_H0T1 + 65536u)
#define OFF_H1T1 (OFF_H1T0 + 65536u)
#define OFF_C0T  (OFF_H1T1 + 65536u)
#define OFF_C1T  (OFF_C0T  + 65536u)
#define OFF_P    (OFF_C1T  + 65536u)         // exp(e) [128][512] (500 used)
#define OFF_PL   (OFF_P    + 65536u)         // l partials [128][2]
#define OFF_PS   (OFF_PL   + 256u)           // s partials [128][2][512]
#define OFF_LB   (OFF_PS   + 131072u)        // logits dbl-buf [2][128][32]
#define OFF_BAR  (OFF_LB   + 8192u)          // barrier cells (1024 u32)

// ---------------- init kernel 1: copies / biases / zeros ----------------
__global__ void initCopy(const float* __restrict__ w_hh0, const float* __restrict__ w_ih1,
                         const float* __restrict__ w_hh1, const float* __restrict__ w_o2c,
                         const float* __restrict__ b_ih0, const float* __restrict__ b_hh0,
                         const float* __restrict__ b_ih1, const float* __restrict__ b_hh1,
                         const float* __restrict__ b_o2c, float* __restrict__ ws)
{
  const unsigned n0 = 2048u*512u;      // WA right (w_hh0)
  const unsigned n1 = 2048u*512u;      // WB left  (w_ih1)
  const unsigned n2 = 2048u*512u;      // WB right (w_hh1)
  const unsigned n3 = 512u*512u;       // GM left
  const unsigned nz = 7u*65536u;       // ST,H0T0,H0T1,H1T0,H1T1,C0T,C1T
  const unsigned NT = n0+n1+n2+n3 + 2048u+2048u+512u + nz + 8192u + 1024u;
  for (unsigned i = blockIdx.x*blockDim.x + threadIdx.x; i < NT; i += gridDim.x*blockDim.x) {
    unsigned j = i;
    if (j < n0) { unsigned r = j>>9, k = j&511u;
      ws[OFF_WA + r*1024u + 512u + k] = w_hh0[j]; continue; }
    j -= n0;
    if (j < n1) { unsigned r = j>>9, k = j&511u;
      ws[OFF_WB + r*1024u + k] = w_ih1[j]; continue; }
    j -= n1;
    if (j < n2) { unsigned r = j>>9, k = j&511u;
      ws[OFF_WB + r*1024u + 512u + k] = w_hh1[j]; continue; }
    j -= n2;
    if (j < n3) { unsigned r = j>>9, k = j&511u;
      ws[OFF_GM + r*1024u + k] = w_o2c[r*1024u + k]; continue; }
    j -= n3;
    if (j < 2048u) { ws[OFF_BA + j] = b_ih0[j] + b_hh0[j]; continue; }
    j -= 2048u;
    if (j < 2048u) { ws[OFF_BB + j] = b_ih1[j] + b_hh1[j]; continue; }
    j -= 2048u;
    if (j < 512u)  { ws[OFF_BG + j] = b_o2c[j]; continue; }
    j -= 512u;
    if (j < nz)    { ws[OFF_ST + j] = 0.f; continue; }
    j -= nz;
    if (j < 8192u) {
      unsigned buf = j>>12, v = j & 31u;
      ws[OFF_LB + j] = (buf==1u && v==0u) ? 1e9f : 0.f;   // argmax -> SOS(=0) at t=0
      continue; }
    j -= 8192u;
    ((unsigned*)(ws + OFF_BAR))[j] = 0u;
  }
}

// ---------------- init kernel 2: folded weight GEMMs ----------------
__global__ void initGemm(const float* __restrict__ w_ih0, const float* __restrict__ w_o2c,
                         const float* __restrict__ wvm, const float* __restrict__ emb,
                         float* __restrict__ ws)
{
  const unsigned n0 = 2048u*512u;   // M  -> WA left
  const unsigned n1 = 512u*512u;    // M2 -> GM right
  const unsigned n2 = 31u*2048u;    // E2G
  const unsigned NT = n0+n1+n2;
  for (unsigned i = blockIdx.x*blockDim.x + threadIdx.x; i < NT; i += gridDim.x*blockDim.x) {
    if (i < n0) {
      unsigned r = i>>9, d = i&511u;
      const float* a = w_ih0 + (size_t)r*1024u + 512u;
      const float* b = wvm + (size_t)d*512u;
      float s = 0.f;
      for (int k = 0; k < 512; ++k) s = fmaf(a[k], b[k], s);
      ws[OFF_WA + r*1024u + d] = s;
    } else if (i < n0+n1) {
      unsigned j = i - n0; unsigned r = j>>9, d = j&511u;
      const float* a = w_o2c + (size_t)r*1024u + 512u;
      const float* b = wvm + (size_t)d*512u;
      float s = 0.f;
      for (int k = 0; k < 512; ++k) s = fmaf(a[k], b[k], s);
      ws[OFF_GM + r*1024u + 512u + d] = s;
    } else {
      unsigned j = i - n0 - n1; unsigned v = j>>11, g = j&2047u;
      const float* a = emb + (size_t)v*512u;
      const float* b = w_ih0 + (size_t)g*1024u;
      float s = 0.f;
      for (int k = 0; k < 512; ++k) s = fmaf(a[k], b[k], s);
      ws[OFF_E2G + v*2048u + g] = s;
    }
  }
}

// ---------------- hierarchical grid barrier ----------------
// cells: cnt[g] at BAR + g*32, root at BAR+256, gen[g] at BAR+512+g*32
__device__ __forceinline__ void gridbar(float* ws, unsigned tgt)
{
  unsigned* base = (unsigned*)(ws + OFF_BAR);
  __syncthreads();
  if (threadIdx.x == 0) {
    const int g = blockIdx.x >> 5;                  // 8 groups of 32 blocks
    unsigned* cnt  = base + g*32;
    unsigned* root = base + 256;
    unsigned* gens = base + 512;
    unsigned old = __hip_atomic_fetch_add(cnt, 1u, __ATOMIC_ACQ_REL, __HIP_MEMORY_SCOPE_AGENT);
    if (old == tgt*32u - 1u) {
      unsigned old2 = __hip_atomic_fetch_add(root, 1u, __ATOMIC_ACQ_REL, __HIP_MEMORY_SCOPE_AGENT);
      if (old2 == tgt*8u - 1u) {
        #pragma unroll
        for (int gg = 0; gg < 8; ++gg)
          __hip_atomic_fetch_add(gens + gg*32, 1u, __ATOMIC_RELEASE, __HIP_MEMORY_SCOPE_AGENT);
      }
    }
    unsigned* mygen = gens + g*32;
    while (__hip_atomic_load(mygen, __ATOMIC_ACQUIRE, __HIP_MEMORY_SCOPE_AGENT) < tgt)
      __builtin_amdgcn_s_sleep(4);
  }
  __syncthreads();
}

__device__ __forceinline__ float sigm(float x) { return 1.f/(1.f + expf(-x)); }

// ---------------- main persistent kernel ----------------
__launch_bounds__(NTHR)
__global__ void speller_main(const float* __restrict__ enc, const float* __restrict__ emb,
                             const float* __restrict__ wk,  const float* __restrict__ bcp,
                             float* __restrict__ ws, float* __restrict__ out)
{
  __shared__ __align__(16) float smem[14592];
  __shared__ int symL[128];
  const int tid = threadIdx.x;
  const int blk = blockIdx.x;
  unsigned bstep = 0;

  float* rawout  = out;                                   // [128][550][31]
  float* attnout = out + (size_t)BATCH*TDEC*VOC;          // [128][550][500]

  for (int t = 0; t < TDEC; ++t) {
    const int p = t & 1;
    float*       h0_cur  = ws + (p ? OFF_H0T1 : OFF_H0T0);
    const float* h0_prev = ws + (p ? OFF_H0T0 : OFF_H0T1);
    float*       h1_cur  = ws + (p ? OFF_H1T1 : OFF_H1T0);
    const float* h1_prev = ws + (p ? OFF_H1T0 : OFF_H1T1);

    // ========== Phase A : argmax feedback + LSTM0 (block owns j0=blk*2) ==========
    {
      const float* Lb = ws + OFF_LB + (size_t)(p^1)*4096u;
      if (blk < 16) {
        if (t > 0) {
          for (int i = tid; i < 248; i += NTHR) {
            int bl = i / 31, v = i - bl*31;
            int bb = blk*8 + bl;
            rawout[((size_t)bb*TDEC + (t-1))*VOC + v] = Lb[bb*32 + v] + bcp[v];
          }
        }
      } else if (blk == 16) {
        float* Lz = ws + OFF_LB + (size_t)p*4096u;
        for (int i = tid; i < 4096; i += NTHR) Lz[i] = 0.f;
      }
      if (tid < 128) {
        float best = -3.4e38f; int sy = 0;
        for (int v = 0; v < VOC; ++v) {
          float f = Lb[tid*32 + v] + bcp[v];
          if (f > best) { best = f; sy = v; }
        }
        symL[tid] = sy;
      }
      const int b  = tid & 127;
      const int kg = tid >> 7;
      const int j0 = blk*2;
      const float* xb = ((kg < 2) ? (ws + OFF_ST + (size_t)kg*256u*128u)
                                  : (h0_prev + (size_t)(kg-2)*256u*128u)) + b;
      const float* wr[8];
      #pragma unroll
      for (int r = 0; r < 8; ++r) {
        int gi = r >> 1, jl = r & 1;
        wr[r] = ws + OFF_WA + (size_t)(gi*512 + j0 + jl)*1024u + kg*256;
      }
      float acc[8] = {0,0,0,0,0,0,0,0};
      for (int k = 0; k < 256; ++k) {
        float xv = xb[(size_t)k*128u];
        #pragma unroll
        for (int r = 0; r < 8; ++r) acc[r] = fmaf(xv, wr[r][k], acc[r]);
      }
      float* lacc = smem;
      __syncthreads();
      #pragma unroll
      for (int r = 0; r < 8; ++r) lacc[(kg*128 + b)*9 + r] = acc[r];
      __syncthreads();
      if (tid < 256) {
        const int bb = tid & 127, jl = tid >> 7;
        const int j = j0 + jl;
        float gv[4];
        #pragma unroll
        for (int gi = 0; gi < 4; ++gi) {
          float s = 0.f;
          #pragma unroll
          for (int kg2 = 0; kg2 < 4; ++kg2) s += lacc[(kg2*128 + bb)*9 + gi*2 + jl];
          s += (ws + OFF_E2G)[(size_t)symL[bb]*2048u + gi*512 + j];
          s += (ws + OFF_BA)[gi*512 + j];
          gv[gi] = s;
        }
        float ig = sigm(gv[0]), fg = sigm(gv[1]);
        float gg = tanhf(gv[2]), og = sigm(gv[3]);
        float cold = (ws + OFF_C0T)[(size_t)j*128 + bb];
        float cnew = fg*cold + ig*gg;
        (ws + OFF_C0T)[(size_t)j*128 + bb] = cnew;
        h0_cur[(size_t)j*128 + bb] = og*tanhf(cnew);
      }
    }
    gridbar(ws, ++bstep);

    // ========== Phase B : LSTM1 ==========
    {
      const int b  = tid & 127;
      const int kg = tid >> 7;
      const int j0 = blk*2;
      const float* xb = ((kg < 2) ? (h0_cur + (size_t)kg*256u*128u)
                                  : (h1_prev + (size_t)(kg-2)*256u*128u)) + b;
      const float* wr[8];
      #pragma unroll
      for (int r = 0; r < 8; ++r) {
        int gi = r >> 1, jl = r & 1;
        wr[r] = ws + OFF_WB + (size_t)(gi*512 + j0 + jl)*1024u + kg*256;
      }
      float acc[8] = {0,0,0,0,0,0,0,0};
      for (int k = 0; k < 256; ++k) {
        float xv = xb[(size_t)k*128u];
        #pragma unroll
        for (int r = 0; r < 8; ++r) acc[r] = fmaf(xv, wr[r][k], acc[r]);
      }
      float* lacc = smem;
      __syncthreads();
      #pragma unroll
      for (int r = 0; r < 8; ++r) lacc[(kg*128 + b)*9 + r] = acc[r];
      __syncthreads();
      if (tid < 256) {
        const int bb = tid & 127, jl = tid >> 7;
        const int j = j0 + jl;
        float gv[4];
        #pragma unroll
        for (int gi = 0; gi < 4; ++gi) {
          float s = 0.f;
          #pragma unroll
          for (int kg2 = 0; kg2 < 4; ++kg2) s += lacc[(kg2*128 + bb)*9 + gi*2 + jl];
          s += (ws + OFF_BB)[gi*512 + j];
          gv[gi] = s;
        }
        float ig = sigm(gv[0]), fg = sigm(gv[1]);
        float gg = tanhf(gv[2]), og = sigm(gv[3]);
        float cold = (ws + OFF_C1T)[(size_t)j*128 + bb];
        float cnew = fg*cold + ig*gg;
        (ws + OFF_C1T)[(size_t)j*128 + bb] = cnew;
        h1_cur[(size_t)j*128 + bb] = og*tanhf(cnew);
      }
    }
    gridbar(ws, ++bstep);

    // ========== Phase C : q + energy + exp + s/l partials (block=(b,tau)) ==========
    {
      const int b = blk >> 1, tau = blk & 1;
      const int tbase = tau*250;
      float* tile = smem;           // [25][520]
      float* qL   = smem + 13000;   // 512
      float* h1L  = smem + 13512;   // 512
      float* pL   = smem + 14024;   // 32
      float* sPst = smem + 14064;   // 512

      h1L[tid] = h1_cur[(size_t)tid*128 + b];
      __syncthreads();
      {
        float s = 0.f;
        const float4* wr4 = (const float4*)(wk + (size_t)tid*512u);
        const float4* h4  = (const float4*)h1L;
        for (int i = 0; i < 128; ++i) {
          float4 w = wr4[i], h = h4[i];
          s = fmaf(w.x,h.x,s); s = fmaf(w.y,h.y,s);
          s = fmaf(w.z,h.z,s); s = fmaf(w.w,h.w,s);
        }
        qL[tid] = s;
      }
      float sacc0 = 0.f, sacc1 = 0.f;
      float ltot = 0.f;
      const int dp = tid & 255, rh = tid >> 8;
      const int cc = tid & 7,  rr = tid >> 3;
      for (int ti = 0; ti < 10; ++ti) {
        const int trow0 = ti*25;
        __syncthreads();
        for (int i = tid; i < 3200; i += NTHR) {
          int r = i >> 7, c = i & 127;
          float4 v = *(const float4*)(enc + ((size_t)b*TENC + tbase + trow0 + r)*EDIM + c*4);
          *(float4*)(tile + r*520 + c*4) = v;
        }
        __syncthreads();
        if (rr < 25) {
          float a = 0.f;
          const float* tr = tile + rr*520;
          #pragma unroll
          for (int i = 0; i < 16; ++i) {
            int d = i*32 + cc*4;
            float4 tv = *(const float4*)(tr + d);
            float4 qv = *(const float4*)(qL + d);
            a = fmaf(tv.x,qv.x,a); a = fmaf(tv.y,qv.y,a);
            a = fmaf(tv.z,qv.z,a); a = fmaf(tv.w,qv.w,a);
          }
          a += __shfl_xor(a, 1); a += __shfl_xor(a, 2); a += __shfl_xor(a, 4);
          if (cc == 0) {
            float pv = expf(a);
            pL[rr] = pv;
            (ws + OFF_P)[(size_t)b*512u + tbase + trow0 + rr] = pv;
          }
        }
        __syncthreads();
        if (tid < 32) {
          float pv = (tid < 25) ? pL[tid] : 0.f;
          pv += __shfl_xor(pv, 1); pv += __shfl_xor(pv, 2); pv += __shfl_xor(pv, 4);
          pv += __shfl_xor(pv, 8); pv += __shfl_xor(pv, 16);
          if (tid == 0) ltot += pv;
        }
        {
          const float* tb2 = tile + dp*2;
          const int r0 = rh ? 13 : 0, r1 = rh ? 25 : 13;
          for (int r = r0; r < r1; ++r) {
            float w = pL[r];
            sacc0 = fmaf(w, tb2[r*520], sacc0);
            sacc1 = fmaf(w, tb2[r*520+1], sacc1);
          }
        }
      }
      __syncthreads();
      if (rh == 1) { sPst[dp*2] = sacc0; sPst[dp*2+1] = sacc1; }
      __syncthreads();
      if (rh == 0) {
        float* psd = ws + OFF_PS + (size_t)(b*2 + tau)*512u;
        psd[dp*2]   = sacc0 + sPst[dp*2];
        psd[dp*2+1] = sacc1 + sPst[dp*2+1];
      }
      if (tid == 0) (ws + OFF_PL)[b*2 + tau] = ltot;
    }
    gridbar(ws, ++bstep);

    // ========== Phase D : ctx combine + o2c + logits + outputs ==========
    {
      const int bt = blk >> 4, it = blk & 15;
      const int b0 = bt*8, i0 = it*32;
      float* xo   = smem;            // [8][1032]
      float* scsL = smem + 8256;     // 8
      float* hidP = smem + 8264;     // [2][256]
      float* hidL = smem + 8776;     // [8][33]
      if (tid < 8) {
        int bb = b0 + tid;
        scsL[tid] = 1.f / ((ws + OFF_PL)[bb*2] + (ws + OFF_PL)[bb*2 + 1]);
      }
      __syncthreads();
      for (int i = tid; i < 4096; i += NTHR) {
        int bl = i & 7, k = i >> 3;
        xo[bl*1032 + k] = h1_cur[(size_t)k*128 + b0 + bl];
      }
      for (int i = tid; i < 4096; i += NTHR) {
        int bl = i & 7, d = i >> 3;
        const float* psd = ws + OFF_PS + (size_t)(b0 + bl)*2u*512u;
        xo[bl*1032 + 512 + d] = (psd[d] + psd[512 + d]) * scsL[bl];
      }
      __syncthreads();
      {
        const int bl = tid & 7, il = (tid >> 3) & 31, kh = tid >> 8;
        float a = 0.f;
        const float4* Gr = (const float4*)(ws + OFF_GM + (size_t)(i0 + il)*1024u + kh*512);
        const float4* xr = (const float4*)(xo + bl*1032 + kh*512);
        for (int k2 = 0; k2 < 128; ++k2) {
          float4 g = Gr[k2], x = xr[k2];
          a = fmaf(g.x,x.x,a); a = fmaf(g.y,x.y,a);
          a = fmaf(g.z,x.z,a); a = fmaf(g.w,x.w,a);
        }
        hidP[(kh << 8) + (tid & 255)] = a;
      }
      __syncthreads();
      if (tid < 256) {
        int bl = tid & 7, il = tid >> 3;
        float h = hidP[tid] + hidP[256 + tid] + (ws + OFF_BG)[i0 + il];
        hidL[bl*33 + il] = fmaxf(h, 0.f);
      }
      if (it == 0) {
        for (int i = tid; i < 4000; i += NTHR) {
          int bl = i / 500, tt = i - bl*500;
          int bb = b0 + bl;
          attnout[((size_t)bb*TDEC + t)*TENC + tt] =
              (ws + OFF_P)[(size_t)bb*512u + tt] * scsL[bl];
        }
        for (int i = tid; i < 4096; i += NTHR) {
          int bl = i & 7, d = i >> 3;
          (ws + OFF_ST)[(size_t)d*128 + b0 + bl] = xo[bl*1032 + 512 + d];
        }
      }
      __syncthreads();
      if (tid < 248) {
        int bl = tid & 7, v = tid >> 3;
        float s = 0.f;
        const float* er = emb + (size_t)v*512u + i0;
        const float* hb = hidL + bl*33;
        #pragma unroll
        for (int ii = 0; ii < 32; ++ii) s = fmaf(hb[ii], er[ii], s);
        float* Lw = ws + OFF_LB + (size_t)p*4096u;
        atomicAdd(&Lw[(b0 + bl)*32 + v], s);
      }
    }
    gridbar(ws, ++bstep);
  } // t loop

  // final logits row (t = 549, parity 1)
  if (blk < 16) {
    const float* Lb = ws + OFF_LB + 4096u;
    for (int i = tid; i < 248; i += NTHR) {
      int bl = i / 31, v = i - bl*31;
      int bb = blk*8 + bl;
      rawout[((size_t)bb*TDEC + (TDEC-1))*VOC + v] = Lb[bb*32 + v] + bcp[v];
    }
  }
}

// ---------------- launch ----------------
extern "C" void kernel_launch(void* const* d_in, const int* in_sizes, int n_in,
                              void* d_out, int out_size, void* d_ws, size_t ws_size,
                              hipStream_t stream)
{
  (void)in_sizes; (void)n_in; (void)out_size; (void)ws_size;
  const float* enc   = (const float*)d_in[0];
  const float* emb   = (const float*)d_in[1];
  const float* w_ih0 = (const float*)d_in[2];
  const float* w_hh0 = (const float*)d_in[3];
  const float* b_ih0 = (const float*)d_in[4];
  const float* b_hh0 = (const float*)d_in[5];
  const float* w_ih1 = (const float*)d_in[6];
  const float* w_hh1 = (const float*)d_in[7];
  const float* b_ih1 = (const float*)d_in[8];
  const float* b_hh1 = (const float*)d_in[9];
  const float* wk    = (const float*)d_in[10];
  const float* wvm   = (const float*)d_in[11];
  const float* w_o2c = (const float*)d_in[12];
  const float* b_o2c = (const float*)d_in[13];
  const float* bcp   = (const float*)d_in[14];
  float* ws   = (float*)d_ws;
  float* outp = (float*)d_out;

  initCopy<<<2048, 256, 0, stream>>>(w_hh0, w_ih1, w_hh1, w_o2c,
                                     b_ih0, b_hh0, b_ih1, b_hh1, b_o2c, ws);
  initGemm<<<2048, 256, 0, stream>>>(w_ih0, w_o2c, wvm, emb, ws);
  speller_main<<<NBLK, NTHR, 0, stream>>>(enc, emb, wk, bcp, ws, outp);
}